// Round 5
// baseline (2852.038 us; speedup 1.0000x reference)
//
#include <hip/hip_runtime.h>
#include <hip/hip_bf16.h>

// Problem constants (from reference)
constexpr int BB = 16;     // batches
constexpr int NN = 8192;   // points
constexpr int SS = 1024;   // samples (FPS)
constexpr int KK = 32;     // kNN
constexpr int BUFC = 256;  // per-wave candidate buffer (keys <= That)

__device__ __forceinline__ float b2f(__hip_bfloat16 h) { return __bfloat162float(h); }

// Monotone map f32 -> u32 (order-preserving, bijective; d is never -0 here).
__device__ __forceinline__ unsigned mkey32(float d) {
    unsigned u = __float_as_uint(d);
    return u ^ (0x80000000u | (unsigned)((int)u >> 31));
}

// Deterministic distance key for point idx vs query (qx,qy,qz,qq).
// Same expression sequence every call -> bit-identical results (IEEE, no FMA).
__device__ __forceinline__ unsigned long long dist_key(const float* __restrict__ pb,
                                                       int idx, float qx, float qy,
                                                       float qz, float qq) {
    float px = pb[idx * 3 + 0];
    float py = pb[idx * 3 + 1];
    float pz = pb[idx * 3 + 2];
    float dot = __fadd_rn(__fadd_rn(__fmul_rn(qx, px), __fmul_rn(qy, py)), __fmul_rn(qz, pz));
    float pp  = __fadd_rn(__fadd_rn(__fmul_rn(px, px), __fmul_rn(py, py)), __fmul_rn(pz, pz));
    float d = __fadd_rn(__fadd_rn(__fmul_rn(-2.0f, dot), qq), pp);
    return ((unsigned long long)mkey32(d) << 32) | (unsigned)idx;
}

// DPP lane-move of a u64 (both halves move identically).
template <int CTRL, int RMASK>
__device__ __forceinline__ unsigned long long dppmove_u64(unsigned long long v) {
    int lo = (int)(unsigned)v, hi = (int)(unsigned)(v >> 32);
    int nlo = __builtin_amdgcn_update_dpp(lo, lo, CTRL, RMASK, 0xf, false);
    int nhi = __builtin_amdgcn_update_dpp(hi, hi, CTRL, RMASK, 0xf, false);
    return ((unsigned long long)(unsigned)nhi << 32) | (unsigned)nlo;
}

// FPS keys are (dist_bits<<32)|~idx with dist_bits <= 0x501502F9 -> as f64 they
// are positive, finite, non-NaN, and bit order == numeric order. v_max_f64
// (1 instr) replaces cmp+2*cndmask in every reduce stage.
template <int CTRL, int RMASK>
__device__ __forceinline__ double dppmax_f64(double v) {
    double m = __longlong_as_double(
        dppmove_u64<CTRL, RMASK>((unsigned long long)__double_as_longlong(v)));
    return fmax(v, m);
}

// Wave64 ALL-LANE max-reduce: ror 1/2/4/8 gives each lane its 16-lane row max
// (circular reduction); shfl_xor 16/32 crosses rows. Every lane ends with the
// wave max -> each wave's unique winner lane (bk==wk) can self-identify.
__device__ __forceinline__ double wave_allmax_f64(double v) {
    v = dppmax_f64<0x121, 0xf>(v);  // row_ror:1
    v = dppmax_f64<0x122, 0xf>(v);  // row_ror:2
    v = dppmax_f64<0x124, 0xf>(v);  // row_ror:4
    v = dppmax_f64<0x128, 0xf>(v);  // row_ror:8
    v = fmax(v, __shfl_xor(v, 16));
    v = fmax(v, __shfl_xor(v, 32));
    return v;
}

// Cross-lane bitonic sort of 64 u64 keys (ascending); lane i ends with i-th smallest.
__device__ __forceinline__ unsigned long long bitonic64(unsigned long long v, int lane) {
#pragma unroll
    for (int k = 2; k <= 64; k <<= 1) {
#pragma unroll
        for (int j = k >> 1; j > 0; j >>= 1) {
            unsigned long long p = __shfl_xor(v, j);
            bool up = ((lane & k) == 0);
            bool lower = ((lane & j) == 0);
            bool take_min = (up == lower);
            v = take_min ? (p < v ? p : v) : (p > v ? p : v);
        }
    }
    return v;
}

// 10-bit -> every-3rd-bit expansion (Morton interleave helper).
__device__ __forceinline__ unsigned expand3(unsigned v) {
    v &= 0x3FFu;
    v = (v | (v << 16)) & 0x030000FFu;
    v = (v | (v << 8))  & 0x0300F00Fu;
    v = (v | (v << 4))  & 0x030C30C3u;
    v = (v | (v << 2))  & 0x09249249u;
    return v;
}

// Carry-select: (k,x,y,z) <- max by key of {(k,x,y,z),(kb,xb,yb,zb)}.
// Keys unique (idx in low bits) -> strict compare, no tie subtleties.
// Correctness-verified in r16's passing run.
__device__ __forceinline__ void sel2(double& k, float& x, float& y, float& z,
                                     double kb, float xb, float yb, float zb) {
    bool g = kb > k;
    k = g ? kb : k;
    x = g ? xb : x;
    y = g ? yb : y;
    z = g ? zb : z;
}

// ---------------------------------------------------------------------------
// K0: dtype detection + upcast to f32 workspace + sentinel fill of d_out.
// ---------------------------------------------------------------------------
__global__ __launch_bounds__(256) void convert_kernel(
    const void* __restrict__ xyz_raw, const void* __restrict__ g1r,
    const void* __restrict__ b1r, const void* __restrict__ g2r,
    const void* __restrict__ b2r, float* __restrict__ xyzf,
    float* __restrict__ params, void* __restrict__ out_raw) {
    const unsigned short* u = (const unsigned short*)xyz_raw;
    unsigned short s = u[2 * (threadIdx.x & 63)];
    int e = (s >> 7) & 0xFF;
    unsigned long long m = __ballot(e >= 100 && e <= 140);
    bool isbf = __popcll(m) > 48;

    const int NT = BB * NN * 3;
    int tid = blockIdx.x * blockDim.x + threadIdx.x;
    int stride = gridDim.x * blockDim.x;
    if (isbf) {
        const __hip_bfloat16* p = (const __hip_bfloat16*)xyz_raw;
        for (int i = tid; i < NT; i += stride) xyzf[i] = b2f(p[i]);
    } else {
        const float* p = (const float*)xyz_raw;
        for (int i = tid; i < NT; i += stride) xyzf[i] = p[i];
    }
    if (blockIdx.x == 0 && threadIdx.x < 85) {
        int t = threadIdx.x;
        if (t == 84) {
            params[84] = isbf ? 1.0f : 0.0f;
        } else {
            const void* src; int off;
            if (t < 6)       { src = g1r; off = t; }
            else if (t < 12) { src = b1r; off = t - 6; }
            else if (t < 48) { src = g2r; off = t - 12; }
            else             { src = b2r; off = t - 48; }
            params[t] = isbf ? b2f(((const __hip_bfloat16*)src)[off])
                             : ((const float*)src)[off];
        }
    }
    if (blockIdx.x == 1 && threadIdx.x < 64) {
        for (int i = threadIdx.x; i < 576; i += 64) {
            if (isbf) ((__hip_bfloat16*)out_raw)[i] = __float2bfloat16(1.0f);
            else      ((float*)out_raw)[i] = 1.0f;
        }
    }
}

// ---------------------------------------------------------------------------
// K1: Farthest point sampling — r19: TWO batches per block, one shared barrier.
//
// Evidence r15-r18: -38% VALU = 0 time; -store = -26us; -50% refresher = -3us.
// Per-step cost (~2100 equiv-cy) is FIXED (barrier arrival/wake + LDS
// round-trip latency + possible low clock), independent of in-step work.
// Amortization: 8 blocks, each advances 2 independent batches per step.
// Their DPP/LDS latencies overlap (independent chains) and ONE barrier
// serves both -> ~2 samples per fixed cost.
//
// LDS blocker (2x96KB coord tables) removed: the only in-loop use of the
// table was the winner-coords gather. Now the reduce is ALL-LANE (ror x4 +
// shfl_xor 16/32), the unique winner lane (bk==wk) writes {key, coords from
// its own registers} to its wave slot pre-barrier; post-barrier a 7-node
// sel2 carry-tree (r16-verified) yields the centroid with no gather and no
// table. Setup reads global directly (L2-resident); both setups run
// sequentially reusing one 32KB sortk, which then becomes samplesA/B.
//
// Exactness: refresh rn-sequence + fminf unchanged; keys (dist<<32)|~idx
// unique -> fmax order-independent, strict compares, exactly one winner per
// wave; coords are verbatim xb bits carried through registers/LDS.
//
// Carried lessons: waves_per_eu(2,2) pins VGPR (r5/r6); multi-CU FPS loses
// (r8/r9); knn fusion loses (r14); in-loop global store costs (r17);
// issue-work cuts alone don't move time (r15/r18).
// ---------------------------------------------------------------------------
__global__ __attribute__((amdgpu_flat_work_group_size(512, 512)))
__attribute__((amdgpu_waves_per_eu(2, 2)))
void fps_kernel(const float* __restrict__ xyzf, float* __restrict__ new_xyz) {
    constexpr int T = 512, P = NN / T;  // 16 contiguous sorted points per thread
    const int b = blockIdx.x, t = threadIdx.x;
    const float* xbA = xyzf + (size_t)(2 * b) * NN * 3;
    const float* xbB = xyzf + (size_t)(2 * b + 1) * NN * 3;

    __shared__ unsigned sortk[NN];        // 32KB: sort keys, then samplesA/B
    __shared__ double skeyL[2][2][8];     // [batch][parity][wave]
    __shared__ float4 scoordL[2][2][8];
    __shared__ float sred[6][8];
    __shared__ float sbb[6];

    const int wave = t >> 6, lane = t & 63;

    // per-batch register state (ni packed 2x16-bit to save VGPRs)
    float pxA[P], pyA[P], pzA[P], dsA[P]; unsigned uniA[P / 2];
    float loxA, loyA, lozA, hixA, hiyA, hizA, cxA, cyA, czA;
    float pxB[P], pyB[P], pzB[P], dsB[P]; unsigned uniB[P / 2];
    float loxB, loyB, lozB, hixB, hiyB, hizB, cxB, cyB, czB;

    auto setup = [&](const float* __restrict__ xb, float (&px)[P], float (&py)[P],
                     float (&pz)[P], float (&ds)[P], unsigned (&uni)[P / 2],
                     float& lox, float& loy, float& loz,
                     float& hix, float& hiy, float& hiz,
                     float& cx, float& cy, float& cz) {
        // --- batch bbox (global reads; L2-resident after first pass) ---
        {
            float mn[3] = {3.4e38f, 3.4e38f, 3.4e38f};
            float mx[3] = {-3.4e38f, -3.4e38f, -3.4e38f};
            for (int j = 0; j < P; j++) {
                int p = t + j * T;
#pragma unroll
                for (int c = 0; c < 3; c++) {
                    float v = xb[p * 3 + c];
                    mn[c] = fminf(mn[c], v);
                    mx[c] = fmaxf(mx[c], v);
                }
            }
#pragma unroll
            for (int o = 32; o > 0; o >>= 1) {
#pragma unroll
                for (int c = 0; c < 3; c++) {
                    mn[c] = fminf(mn[c], __shfl_xor(mn[c], o));
                    mx[c] = fmaxf(mx[c], __shfl_xor(mx[c], o));
                }
            }
            if (lane == 0) {
#pragma unroll
                for (int c = 0; c < 3; c++) { sred[c][wave] = mn[c]; sred[3 + c][wave] = mx[c]; }
            }
            __syncthreads();
            if (t < 6) {
                bool ismin = t < 3;
                float v = sred[t][0];
                for (int w = 1; w < 8; w++) v = ismin ? fminf(v, sred[t][w]) : fmaxf(v, sred[t][w]);
                sbb[t] = v;
            }
            __syncthreads();
        }
        // --- Morton keys (6 bits/axis; affects pruning rate only) ---
        {
            float bx = sbb[0], by = sbb[1], bz = sbb[2];
            float qsx = 63.0f / fmaxf(sbb[3] - bx, 1e-9f);
            float qsy = 63.0f / fmaxf(sbb[4] - by, 1e-9f);
            float qsz = 63.0f / fmaxf(sbb[5] - bz, 1e-9f);
            for (int p = t; p < NN; p += T) {
                unsigned qx = (unsigned)min(63, (int)((xb[p * 3 + 0] - bx) * qsx));
                unsigned qy = (unsigned)min(63, (int)((xb[p * 3 + 1] - by) * qsy));
                unsigned qz = (unsigned)min(63, (int)((xb[p * 3 + 2] - bz) * qsz));
                unsigned m = (expand3(qx) << 2) | (expand3(qy) << 1) | expand3(qz);
                sortk[p] = (m << 13) | (unsigned)p;
            }
            __syncthreads();
            for (unsigned k = 2; k <= (unsigned)NN; k <<= 1) {
                for (unsigned j = k >> 1; j > 0; j >>= 1) {
#pragma unroll
                    for (int r = 0; r < NN / 2 / T; r++) {  // 8
                        unsigned gid = (unsigned)(r * T + t);
                        unsigned i = ((gid & ~(j - 1)) << 1) | (gid & (j - 1));
                        unsigned p2 = i | j;
                        unsigned a = sortk[i], c2 = sortk[p2];
                        bool up = ((i & k) == 0);
                        if ((a > c2) == up) { sortk[i] = c2; sortk[p2] = a; }
                    }
                    __syncthreads();
                }
            }
        }
        // --- load 16 sorted points -> regs; exact per-thread bbox ---
        lox = 3.4e38f; loy = 3.4e38f; loz = 3.4e38f;
        hix = -3.4e38f; hiy = -3.4e38f; hiz = -3.4e38f;
#pragma unroll
        for (int j = 0; j < P; j++) {
            unsigned oi = sortk[t * P + j] & 8191u;
            float x = xb[oi * 3 + 0];
            float y = xb[oi * 3 + 1];
            float z = xb[oi * 3 + 2];
            px[j] = x; py[j] = y; pz[j] = z;
            ds[j] = 1e10f;
            if ((j & 1) == 0) uni[j >> 1] = oi; else uni[j >> 1] |= (oi << 16);
            lox = fminf(lox, x); hix = fmaxf(hix, x);
            loy = fminf(loy, y); hiy = fmaxf(hiy, y);
            loz = fminf(loz, z); hiz = fmaxf(hiz, z);
        }
        cx = xb[0]; cy = xb[1]; cz = xb[2];
        __syncthreads();   // sortk reads done -> safe to overwrite/reuse
    };

    setup(xbA, pxA, pyA, pzA, dsA, uniA, loxA, loyA, lozA, hixA, hiyA, hizA, cxA, cyA, czA);
    setup(xbB, pxB, pyB, pzB, dsB, uniB, loxB, loyB, lozB, hixB, hiyB, hizB, cxB, cyB, czB);

    float* samplesA = (float*)sortk;          // 12KB
    float* samplesB = samplesA + SS * 3;      // next 12KB (sortk is 32KB)

    if (t == 0) {
        samplesA[0] = cxA; samplesA[1] = cyA; samplesA[2] = czA;
        samplesB[0] = cxB; samplesB[1] = cyB; samplesB[2] = czB;
    }

    double bkA = 0.0, bkB = 0.0;   // cached candidate keys (exact while skipping)
    float tbA = 1e10f, tbB = 1e10f;

    for (int step = 1; step < SS; step++) {
        const int par = step & 1;

        // ================= batch A: prune/refresh + reduce + winner-write
        {
            float ax = fmaxf(fmaxf(__fsub_rn(loxA, cxA), __fsub_rn(cxA, hixA)), 0.0f);
            float ay = fmaxf(fmaxf(__fsub_rn(loyA, cyA), __fsub_rn(cyA, hiyA)), 0.0f);
            float az = fmaxf(fmaxf(__fsub_rn(lozA, czA), __fsub_rn(czA, hizA)), 0.0f);
            float lbd = ax * ax + ay * ay + az * az;
            if (lbd * 0.999f < tbA) {
                double kk[P];
#pragma unroll
                for (int j = 0; j < P; j++) {
                    float dx = __fsub_rn(pxA[j], cxA);
                    float dy = __fsub_rn(pyA[j], cyA);
                    float dz = __fsub_rn(pzA[j], czA);
                    float d = __fadd_rn(__fadd_rn(__fmul_rn(dx, dx), __fmul_rn(dy, dy)),
                                        __fmul_rn(dz, dz));
                    float mm = fminf(dsA[j], d);
                    dsA[j] = mm;
                    unsigned oi = (uniA[j >> 1] >> ((j & 1) * 16)) & 0xFFFFu;
                    kk[j] = __hiloint2double(__float_as_int(mm), (int)~oi);
                }
#pragma unroll
                for (int w2 = P / 2; w2 > 0; w2 >>= 1)
#pragma unroll
                    for (int j = 0; j < w2; j++) kk[j] = fmax(kk[j], kk[j + w2]);
                bkA = kk[0];
                tbA = __uint_as_float((unsigned)__double2hiint(bkA));
            }
            double wk = wave_allmax_f64(bkA);
            if (bkA == wk) {   // exactly one lane per wave (keys unique)
                unsigned widx = ~(unsigned)(unsigned long long)__double_as_longlong(bkA);
                float wx = pxA[0], wy = pyA[0], wz = pzA[0];
#pragma unroll
                for (int j = 1; j < P; j++) {
                    unsigned oi = (uniA[j >> 1] >> ((j & 1) * 16)) & 0xFFFFu;
                    bool m = (oi == widx);
                    wx = m ? pxA[j] : wx; wy = m ? pyA[j] : wy; wz = m ? pzA[j] : wz;
                }
                skeyL[0][par][wave] = bkA;
                scoordL[0][par][wave] = make_float4(wx, wy, wz, 0.0f);
            }
        }
        // ================= batch B
        {
            float ax = fmaxf(fmaxf(__fsub_rn(loxB, cxB), __fsub_rn(cxB, hixB)), 0.0f);
            float ay = fmaxf(fmaxf(__fsub_rn(loyB, cyB), __fsub_rn(cyB, hiyB)), 0.0f);
            float az = fmaxf(fmaxf(__fsub_rn(lozB, czB), __fsub_rn(czB, hizB)), 0.0f);
            float lbd = ax * ax + ay * ay + az * az;
            if (lbd * 0.999f < tbB) {
                double kk[P];
#pragma unroll
                for (int j = 0; j < P; j++) {
                    float dx = __fsub_rn(pxB[j], cxB);
                    float dy = __fsub_rn(pyB[j], cyB);
                    float dz = __fsub_rn(pzB[j], czB);
                    float d = __fadd_rn(__fadd_rn(__fmul_rn(dx, dx), __fmul_rn(dy, dy)),
                                        __fmul_rn(dz, dz));
                    float mm = fminf(dsB[j], d);
                    dsB[j] = mm;
                    unsigned oi = (uniB[j >> 1] >> ((j & 1) * 16)) & 0xFFFFu;
                    kk[j] = __hiloint2double(__float_as_int(mm), (int)~oi);
                }
#pragma unroll
                for (int w2 = P / 2; w2 > 0; w2 >>= 1)
#pragma unroll
                    for (int j = 0; j < w2; j++) kk[j] = fmax(kk[j], kk[j + w2]);
                bkB = kk[0];
                tbB = __uint_as_float((unsigned)__double2hiint(bkB));
            }
            double wk = wave_allmax_f64(bkB);
            if (bkB == wk) {
                unsigned widx = ~(unsigned)(unsigned long long)__double_as_longlong(bkB);
                float wx = pxB[0], wy = pyB[0], wz = pzB[0];
#pragma unroll
                for (int j = 1; j < P; j++) {
                    unsigned oi = (uniB[j >> 1] >> ((j & 1) * 16)) & 0xFFFFu;
                    bool m = (oi == widx);
                    wx = m ? pxB[j] : wx; wy = m ? pyB[j] : wy; wz = m ? pzB[j] : wz;
                }
                skeyL[1][par][wave] = bkB;
                scoordL[1][par][wave] = make_float4(wx, wy, wz, 0.0f);
            }
        }

        __syncthreads();   // ONE barrier serves both batches

        // ================= finish A: carry-tree over 8 slots (no gather)
        {
            double K0 = skeyL[0][par][0], K1 = skeyL[0][par][1], K2 = skeyL[0][par][2], K3 = skeyL[0][par][3];
            double K4 = skeyL[0][par][4], K5 = skeyL[0][par][5], K6 = skeyL[0][par][6], K7 = skeyL[0][par][7];
            float4 C0 = scoordL[0][par][0], C1 = scoordL[0][par][1], C2 = scoordL[0][par][2], C3 = scoordL[0][par][3];
            float4 C4 = scoordL[0][par][4], C5 = scoordL[0][par][5], C6 = scoordL[0][par][6], C7 = scoordL[0][par][7];
            sel2(K0, C0.x, C0.y, C0.z, K1, C1.x, C1.y, C1.z);
            sel2(K2, C2.x, C2.y, C2.z, K3, C3.x, C3.y, C3.z);
            sel2(K4, C4.x, C4.y, C4.z, K5, C5.x, C5.y, C5.z);
            sel2(K6, C6.x, C6.y, C6.z, K7, C7.x, C7.y, C7.z);
            sel2(K0, C0.x, C0.y, C0.z, K2, C2.x, C2.y, C2.z);
            sel2(K4, C4.x, C4.y, C4.z, K6, C6.x, C6.y, C6.z);
            sel2(K0, C0.x, C0.y, C0.z, K4, C4.x, C4.y, C4.z);
            cxA = C0.x; cyA = C0.y; czA = C0.z;
        }
        // ================= finish B
        {
            double K0 = skeyL[1][par][0], K1 = skeyL[1][par][1], K2 = skeyL[1][par][2], K3 = skeyL[1][par][3];
            double K4 = skeyL[1][par][4], K5 = skeyL[1][par][5], K6 = skeyL[1][par][6], K7 = skeyL[1][par][7];
            float4 C0 = scoordL[1][par][0], C1 = scoordL[1][par][1], C2 = scoordL[1][par][2], C3 = scoordL[1][par][3];
            float4 C4 = scoordL[1][par][4], C5 = scoordL[1][par][5], C6 = scoordL[1][par][6], C7 = scoordL[1][par][7];
            sel2(K0, C0.x, C0.y, C0.z, K1, C1.x, C1.y, C1.z);
            sel2(K2, C2.x, C2.y, C2.z, K3, C3.x, C3.y, C3.z);
            sel2(K4, C4.x, C4.y, C4.z, K5, C5.x, C5.y, C5.z);
            sel2(K6, C6.x, C6.y, C6.z, K7, C7.x, C7.y, C7.z);
            sel2(K0, C0.x, C0.y, C0.z, K2, C2.x, C2.y, C2.z);
            sel2(K4, C4.x, C4.y, C4.z, K6, C6.x, C6.y, C6.z);
            sel2(K0, C0.x, C0.y, C0.z, K4, C4.x, C4.y, C4.z);
            cxB = C0.x; cyB = C0.y; czB = C0.z;
        }
        if (t == 0) {
            samplesA[step * 3 + 0] = cxA; samplesA[step * 3 + 1] = cyA; samplesA[step * 3 + 2] = czA;
            samplesB[step * 3 + 0] = cxB; samplesB[step * 3 + 1] = cyB; samplesB[step * 3 + 2] = czB;
        }
    }

    __syncthreads();
    // batches 2b and 2b+1 are contiguous in new_xyz, samplesA/B contiguous in
    // LDS -> one coalesced 24KB write.
    float* o = new_xyz + (size_t)(2 * b) * SS * 3;
    for (int i = t; i < 2 * SS * 3; i += T) o[i] = samplesA[i];
}

// ---------------------------------------------------------------------------
// K2 (RECOMPUTE): kNN via exact threshold selection, one wave per query,
// NO per-lane key array.
// r13/r14 LESSON: mk[128] spilled to scratch -> 2.2 GB HBM traffic (32KB per
// query written+read); this was the entire ~300 us knn cost in r4-r10.
// Fix: pass 1 tracks only the lane-min key; pass 2 RECOMPUTES each key for
// the compaction test. IEEE ops on immutable inputs -> bit-identical keys ->
// selection unchanged (r14: absmax identical). Extra VALU (~1 extra pass
// over L2-resident cloud) is far cheaper than scratch round-trips.
// ---------------------------------------------------------------------------
__global__ __launch_bounds__(256, 2) void knn_kernel(const float* __restrict__ xyzf,
                                                     const float* __restrict__ new_xyz,
                                                     float* __restrict__ A,
                                                     double* __restrict__ qstats) {
    __shared__ unsigned long long buf[4][BUFC];
    const int t = threadIdx.x;
    const int lane = t & 63, wv = t >> 6;
    const int w = blockIdx.x * 4 + wv;          // global wave id = query id
    const int b = w >> 10, s = w & 1023;

    const float* q = new_xyz + ((size_t)b * SS + s) * 3;
    float qx = q[0], qy = q[1], qz = q[2];
    float qq = __fadd_rn(__fadd_rn(__fmul_rn(qx, qx), __fmul_rn(qy, qy)), __fmul_rn(qz, qz));

    const float* pb = xyzf + (size_t)b * NN * 3;
    const unsigned long long ltmask = (1ull << lane) - 1ull;

    // pass 1: lane-min key only (no storage)
    unsigned long long lmin = ~0ull;
    for (int j = 0; j < 128; j++) {
        unsigned long long key = dist_key(pb, j * 64 + lane, qx, qy, qz, qq);
        lmin = key < lmin ? key : lmin;
    }

    unsigned long long vs = bitonic64(lmin, lane);
    unsigned long long That = __shfl(vs, 31);

    // pass 2: recompute keys, compact keys <= That into LDS
    for (int i = lane; i < BUFC; i += 64) buf[wv][i] = ~0ull;
    int base = 0;
    for (int j = 0; j < 128; j++) {
        unsigned long long key = dist_key(pb, j * 64 + lane, qx, qy, qz, qq);
        bool f = key <= That;
        unsigned long long bal = __ballot(f);
        int pos = base + __popcll(bal & ltmask);
        if (f && pos < BUFC) buf[wv][pos] = key;
        base += __popcll(bal);
    }

    // rare recovery: tighten threshold (recompute inside search)
    if (base > BUFC) {
        unsigned lo = 0, hi = (unsigned)(That >> 32);
        for (int it = 0; it < 32; it++) {
            unsigned mid = lo + ((hi - lo) >> 1);
            int c = 0;
            for (int j = 0; j < 128; j++) {
                unsigned long long key = dist_key(pb, j * 64 + lane, qx, qy, qz, qq);
                c += ((unsigned)(key >> 32) <= mid) ? 1 : 0;
            }
#pragma unroll
            for (int o = 32; o > 0; o >>= 1) c += __shfl_xor(c, o);
            if (c >= 32) hi = mid; else lo = mid + 1;
        }
        That = ((unsigned long long)hi << 32) | 0xFFFFFFFFull;
        for (int i = lane; i < BUFC; i += 64) buf[wv][i] = ~0ull;
        base = 0;
        for (int j = 0; j < 128; j++) {
            unsigned long long key = dist_key(pb, j * 64 + lane, qx, qy, qz, qq);
            bool f = key <= That;
            unsigned long long bal = __ballot(f);
            int pos = base + __popcll(bal & ltmask);
            if (f && pos < BUFC) buf[wv][pos] = key;
            base += __popcll(bal);
        }
        if (base > BUFC) base = BUFC;
    }

    int M = base;
    unsigned long long kept = ~0ull;
    if (M <= 64) {
        unsigned long long v = (lane < M) ? buf[wv][lane] : ~0ull;
        v = bitonic64(v, lane);
        kept = v;
    } else {
        unsigned long long c0 = buf[wv][lane];
        unsigned long long c1 = buf[wv][64 + lane];
        unsigned long long c2 = buf[wv][128 + lane];
        unsigned long long c3 = buf[wv][192 + lane];
        for (int r = 0; r < KK; r++) {
            unsigned long long m01 = c0 < c1 ? c0 : c1;
            unsigned long long m23 = c2 < c3 ? c2 : c3;
            unsigned long long mm = m01 < m23 ? m01 : m23;
#pragma unroll
            for (int o = 32; o > 0; o >>= 1) {
                unsigned long long t2 = __shfl_xor(mm, o);
                mm = t2 < mm ? t2 : mm;
            }
            if (lane == r) kept = mm;
            c0 = (c0 == mm) ? ~0ull : c0;
            c1 = (c1 == mm) ? ~0ull : c1;
            c2 = (c2 == mm) ? ~0ull : c2;
            c3 = (c3 == mm) ? ~0ull : c3;
        }
    }

    bool act = (lane < KK);
    float gx = 0.0f, gy = 0.0f, gz = 0.0f;
    if (act) {
        unsigned nidx = (unsigned)kept;
        gx = pb[nidx * 3 + 0];
        gy = pb[nidx * 3 + 1];
        gz = pb[nidx * 3 + 2];
    }
    float dx = __fsub_rn(gx, qx);
    float dy = __fsub_rn(gy, qy);
    float dz = __fsub_rn(gz, qz);
    float mx = act ? dx : -3.402823466e38f;
    float my = act ? dy : -3.402823466e38f;
    float mz = act ? dz : -3.402823466e38f;
    float sx = act ? dx : 0.0f;
    float sy = act ? dy : 0.0f;
    float sz = act ? dz : 0.0f;
    double s1 = act ? ((double)dx + (double)dy + (double)dz) : 0.0;
    double s2 = act ? ((double)dx * dx + (double)dy * dy + (double)dz * dz) : 0.0;
#pragma unroll
    for (int o = 32; o > 0; o >>= 1) {
        mx = fmaxf(mx, __shfl_xor(mx, o));
        my = fmaxf(my, __shfl_xor(my, o));
        mz = fmaxf(mz, __shfl_xor(mz, o));
        sx += __shfl_xor(sx, o);
        sy += __shfl_xor(sy, o);
        sz += __shfl_xor(sz, o);
        s1 += __shfl_xor(s1, o);
        s2 += __shfl_xor(s2, o);
    }
    if (lane == 0) {
        float* a = A + ((size_t)b * SS + s) * 3;
        a[0] = __fadd_rn(mx, __fmul_rn(sx, 0.03125f));
        a[1] = __fadd_rn(my, __fmul_rn(sy, 0.03125f));
        a[2] = __fadd_rn(mz, __fmul_rn(sz, 0.03125f));
        qstats[2 * w + 0] = s1;
        qstats[2 * w + 1] = s2;
    }
}

// ---------------------------------------------------------------------------
// K2b: reduce per-query stats -> global stats[0..1]. One block.
// ---------------------------------------------------------------------------
__global__ __launch_bounds__(256) void reduce_stats_kernel(const double* __restrict__ qstats,
                                                           double* __restrict__ stats) {
    __shared__ double r1[4], r2[4];
    int t = threadIdx.x;
    double a = 0.0, bsum = 0.0;
    for (int i = t; i < BB * SS; i += 256) { a += qstats[2 * i]; bsum += qstats[2 * i + 1]; }
#pragma unroll
    for (int o = 32; o > 0; o >>= 1) { a += __shfl_xor(a, o); bsum += __shfl_xor(bsum, o); }
    int wv = t >> 6, ln = t & 63;
    if (ln == 0) { r1[wv] = a; r2[wv] = bsum; }
    __syncthreads();
    if (t == 0) {
        stats[0] = r1[0] + r1[1] + r1[2] + r1[3];
        stats[1] = r2[0] + r2[1] + r2[2] + r2[3];
    }
}

// ---------------------------------------------------------------------------
// K3: lc[b,c,s]: c<3 -> A/(std+1e-5); c>=3 -> 2*new_xyz. Accumulate BN1 sums.
// ---------------------------------------------------------------------------
__global__ __launch_bounds__(256) void lc_kernel(const float* __restrict__ new_xyz,
                                                 const float* __restrict__ A,
                                                 const double* __restrict__ stats,
                                                 float* __restrict__ lc,
                                                 double* __restrict__ bn1acc) {
    __shared__ double red[4];
    const int b = blockIdx.x / 6, c = blockIdx.x % 6;
    const int t = threadIdx.x;
    const double n = (double)BB * SS * KK * 3;
    double sd = stats[0], sq = stats[1];
    double var = (sq - sd * sd / n) / (n - 1.0);
    float stdv = (float)sqrt(var);
    float denom = __fadd_rn(stdv, 1e-5f);

    double s1 = 0.0, s2 = 0.0;
    for (int r = 0; r < 4; r++) {
        int s = r * 256 + t;
        float v;
        if (c < 3) {
            v = A[((size_t)b * SS + s) * 3 + c] / denom;
        } else {
            float ww = new_xyz[((size_t)b * SS + s) * 3 + (c - 3)];
            v = __fadd_rn(ww, ww);
        }
        lc[((size_t)b * 6 + c) * SS + s] = v;
        s1 += (double)v;
        s2 += (double)v * (double)v;
    }
#pragma unroll
    for (int off = 32; off > 0; off >>= 1) { s1 += __shfl_down(s1, off); s2 += __shfl_down(s2, off); }
    int wv = t >> 6, ln = t & 63;
    if (ln == 0) red[wv] = s1;
    __syncthreads();
    if (t == 0) atomicAdd(&bn1acc[c * 2 + 0], red[0] + red[1] + red[2] + red[3]);
    __syncthreads();
    if (ln == 0) red[wv] = s2;
    __syncthreads();
    if (t == 0) atomicAdd(&bn1acc[c * 2 + 1], red[0] + red[1] + red[2] + red[3]);
}

// ---------------------------------------------------------------------------
// K4a: per-batch: y = relu(BN1(lc)), then 6x6 safe cdist over S. 16 blocks.
// ---------------------------------------------------------------------------
__global__ __launch_bounds__(256) void cdist_kernel(const float* __restrict__ lc,
                                                    const double* __restrict__ bn1acc,
                                                    const float* __restrict__ params,
                                                    float* __restrict__ tf) {
    __shared__ float sy[6 * SS];
    const int b = blockIdx.x, t = threadIdx.x;
    float mean[6], sde[6], gg[6], bt[6];
    const double n = (double)BB * SS;
#pragma unroll
    for (int c = 0; c < 6; c++) {
        double m = bn1acc[c * 2 + 0] / n;
        double v = bn1acc[c * 2 + 1] / n - m * m;
        mean[c] = (float)m;
        sde[c] = sqrtf((float)v + 1e-5f);
        gg[c] = params[c];
        bt[c] = params[6 + c];
    }
    for (int r = 0; r < 24; r++) {
        int g = r * 256 + t;
        int c = g >> 10;
        float v = lc[(size_t)b * 6 * SS + g];
        float y = (v - mean[c]) / sde[c] * gg[c] + bt[c];
        sy[g] = fmaxf(y, 0.0f);
    }
    __syncthreads();
    if (t < 6) tf[b * 36 + t * 7] = 0.0f;

    const int w = t >> 6, lane = t & 63;
    const int PI[15] = {0,0,0,0,0,1,1,1,1,2,2,2,3,3,4};
    const int PJ[15] = {1,2,3,4,5,2,3,4,5,3,4,5,4,5,5};
    for (int r = 0; r < 4; r++) {
        int p = w + r * 4;
        if (p < 15) {
            int i = PI[p], j = PJ[p];
            float acc = 0.0f;
            for (int m2 = 0; m2 < 16; m2++) {
                int s = lane + m2 * 64;
                float d = sy[i * SS + s] - sy[j * SS + s];
                acc += d * d;
            }
#pragma unroll
            for (int off = 32; off > 0; off >>= 1) acc += __shfl_down(acc, off);
            if (lane == 0) {
                float v = acc > 0.0f ? sqrtf(acc) : 0.0f;
                const float FACTOR = 1.0f;
                tf[b * 36 + i * 6 + j] = (j == i + 1) ? v * FACTOR : v;
                tf[b * 36 + j * 6 + i] = v;
            }
        }
    }
}

// ---------------------------------------------------------------------------
// K4b: BN2 over batch per feature + relu -> out [16,36] (dtype per params[84]).
// ---------------------------------------------------------------------------
__global__ __launch_bounds__(64) void bn2_kernel(const float* __restrict__ tf,
                                                 const float* __restrict__ params,
                                                 void* __restrict__ out_raw) {
    int f = threadIdx.x;
    if (f >= 36) return;
    bool isbf = params[84] != 0.0f;
    float x[16]; float sum = 0.0f;
#pragma unroll
    for (int b = 0; b < 16; b++) { x[b] = tf[b * 36 + f]; sum += x[b]; }
    float mean = sum * 0.0625f;
    float vs = 0.0f;
#pragma unroll
    for (int b = 0; b < 16; b++) { float d = x[b] - mean; vs += d * d; }
    float var = vs * 0.0625f;
    float denom = sqrtf(var + 1e-5f);
    float g = params[12 + f], bb = params[48 + f];
#pragma unroll
    for (int b = 0; b < 16; b++) {
        float y = (x[b] - mean) / denom * g + bb;
        y = fmaxf(y, 0.0f);
        if (isbf) ((__hip_bfloat16*)out_raw)[b * 36 + f] = __float2bfloat16(y);
        else      ((float*)out_raw)[b * 36 + f] = y;
    }
}

// ---------------------------------------------------------------------------
// Workspace layout (bytes):
//   0        : xyzf     float[16*8192*3]   (1572864)
//   1572864  : new_xyz  float[16*1024*3]   (196608)
//   1769472  : A        float[16*1024*3]   (196608)
//   1966080  : lc       float[16*6*1024]   (393216)
//   2359296  : tfcw     float[16*36]       (2304)
//   2361600  : stats    double[14]
//   2361712  : params   float[85]
//   2362112  : qstats   double[16384*2]    (262144)
// ---------------------------------------------------------------------------
extern "C" void kernel_launch(void* const* d_in, const int* in_sizes, int n_in,
                              void* d_out, int out_size, void* d_ws, size_t ws_size,
                              hipStream_t stream) {
    const void* xyz_raw = d_in[0];
    const void* g1r = d_in[1]; const void* b1r = d_in[2];
    const void* g2r = d_in[3]; const void* b2r = d_in[4];
    {
        const void* six[2] = {nullptr, nullptr}; int n6 = 0;
        const void* t36[2] = {nullptr, nullptr}; int n36 = 0;
        const void* big = nullptr;
        for (int i = 0; i < n_in; i++) {
            if (in_sizes[i] == BB * NN * 3) big = d_in[i];
            else if (in_sizes[i] == 6  && n6  < 2) six[n6++]  = d_in[i];
            else if (in_sizes[i] == 36 && n36 < 2) t36[n36++] = d_in[i];
        }
        if (big && n6 == 2 && n36 == 2) {
            xyz_raw = big; g1r = six[0]; b1r = six[1]; g2r = t36[0]; b2r = t36[1];
        }
    }

    char* ws = (char*)d_ws;
    float* xyzf    = (float*)(ws + 0);
    float* new_xyz = (float*)(ws + 1572864);
    float* A       = (float*)(ws + 1769472);
    float* lc      = (float*)(ws + 1966080);
    float* tf      = (float*)(ws + 2359296);
    double* stats  = (double*)(ws + 2361600);
    double* bn1acc = stats + 2;
    float* params  = (float*)(ws + 2361712);
    double* qstats = (double*)(ws + 2362112);

    hipMemsetAsync(stats, 0, 14 * sizeof(double), stream);
    hipLaunchKernelGGL(convert_kernel, dim3(512), dim3(256), 0, stream,
                       xyz_raw, g1r, b1r, g2r, b2r, xyzf, params, d_out);
    hipLaunchKernelGGL(fps_kernel,          dim3(8),    dim3(512), 0, stream, xyzf, new_xyz);
    hipLaunchKernelGGL(knn_kernel,          dim3(4096), dim3(256), 0, stream, xyzf, new_xyz, A, qstats);
    hipLaunchKernelGGL(reduce_stats_kernel, dim3(1),    dim3(256), 0, stream, qstats, stats);
    hipLaunchKernelGGL(lc_kernel,           dim3(96),   dim3(256), 0, stream, new_xyz, A, stats, lc, bn1acc);
    hipLaunchKernelGGL(cdist_kernel,        dim3(16),   dim3(256), 0, stream, lc, bn1acc, params, tf);
    hipLaunchKernelGGL(bn2_kernel,          dim3(1),    dim3(64),  0, stream, tf, params, d_out);

    (void)in_sizes; (void)n_in; (void)out_size; (void)ws_size;
}